// Round 1
// baseline (203.521 us; speedup 1.0000x reference)
//
#include <hip/hip_runtime.h>
#include <stdint.h>

typedef unsigned short u16;
typedef unsigned int   u32;
typedef float   f32x4  __attribute__((ext_vector_type(4)));
typedef float   f32x16 __attribute__((ext_vector_type(16)));
typedef __bf16  bf16x8 __attribute__((ext_vector_type(8)));
typedef u32     u32x4  __attribute__((ext_vector_type(4)));

union BF8 { bf16x8 v; u16 s[8]; u32x4 q; };

__device__ __forceinline__ u16 f2b_rne(float f) {
    u32 u = __builtin_bit_cast(u32, f);
    u32 r = u + 0x7FFFu + ((u >> 16) & 1u);
    return (u16)(r >> 16);
}
__device__ __forceinline__ float b2f(u16 h) {
    u32 u = ((u32)h) << 16;
    return __builtin_bit_cast(float, u);
}
__device__ __forceinline__ bf16x8 ld_bf8(const u16* p) {
    BF8 t; t.q = *(const u32x4*)p; return t.v;
}
__device__ __forceinline__ f32x16 zero16() {
    f32x16 z;
#pragma unroll
    for (int i = 0; i < 16; i++) z[i] = 0.f;
    return z;
}
__device__ __forceinline__ f32x4 zero4() {
    f32x4 z;
#pragma unroll
    for (int i = 0; i < 4; i++) z[i] = 0.f;
    return z;
}

// ---------------------------------------------------------------------------
// prep: transpose + hi/lo split Wq/Wk, transpose Wv, bf16 lin_w, mask -> bias2
// bias2 is in log2 domain: -1000 * log2(e)
// ---------------------------------------------------------------------------
__global__ __launch_bounds__(256) void prep_kernel(
    const float* wq, const float* wk, const float* wv,
    const float* lw, const int* mask,
    u16* wq_th, u16* wq_tl, u16* wk_th, u16* wk_tl,
    u16* wv_t, u16* lwb, float* bias2)
{
    int t = blockIdx.x * 256 + threadIdx.x;
    if (t < 16384) {
        int n = t >> 7, i = t & 127;
        float q = wq[i * 128 + n];
        float k = wk[i * 128 + n];
        float v = wv[i * 128 + n];
        u16 qh = f2b_rne(q); wq_th[t] = qh; wq_tl[t] = f2b_rne(q - b2f(qh));
        u16 kh = f2b_rne(k); wk_th[t] = kh; wk_tl[t] = f2b_rne(k - b2f(kh));
        wv_t[t] = f2b_rne(v);
        lwb[t] = f2b_rne(lw[t]);   // lin_w used as [o][i] directly, no transpose
    }
    if (t < 8192)
        bias2[t] = (mask[t] == 0) ? -1442.6950408889634f : 0.0f;
}

// ---------------------------------------------------------------------------
// projection: Q,K as bf16 hi+lo pairs (x also split hi/lo -> ~fp32 accuracy),
// V transposed per-row into VT[b][n][s] (n = h*16+d) for the PV B-operand.
// grid: (64 row-blocks, 3 types), block 256 (4 waves x 32 rows), 4 col tiles.
// ---------------------------------------------------------------------------
__global__ __launch_bounds__(256) void proj_kernel(
    const float* x,
    const u16* wq_th, const u16* wq_tl,
    const u16* wk_th, const u16* wk_tl,
    const u16* wv_t,
    u16* Qh, u16* Ql, u16* Kh, u16* Kl, u16* VT)
{
    int typ  = blockIdx.y;                 // 0=Q 1=K 2=V
    int wave = threadIdx.x >> 6, lane = threadIdx.x & 63;
    int m = lane & 31, kg = lane >> 5;
    int r0 = blockIdx.x * 128 + wave * 32;

    const u16* wh = (typ == 0) ? wq_th : (typ == 1) ? wk_th : wv_t;
    const u16* wl = (typ == 0) ? wq_tl : wk_tl;

    f32x16 acc[4];
#pragma unroll
    for (int ct = 0; ct < 4; ct++) acc[ct] = zero16();

    for (int kk = 0; kk < 128; kk += 16) {
        const float* xp = x + (r0 + m) * 128 + kk + kg * 8;
        BF8 ah, al;
#pragma unroll
        for (int j = 0; j < 8; j++) {
            float xv = xp[j];
            u16 hb = f2b_rne(xv);
            ah.s[j] = hb;
            al.s[j] = f2b_rne(xv - b2f(hb));
        }
#pragma unroll
        for (int ct = 0; ct < 4; ct++) {
            const u16* bp = wh + (ct * 32 + m) * 128 + kk + kg * 8;
            bf16x8 bh = ld_bf8(bp);
            acc[ct] = __builtin_amdgcn_mfma_f32_32x32x16_bf16(ah.v, bh, acc[ct], 0, 0, 0);
            if (typ < 2) {
                bf16x8 bl = ld_bf8(wl + (ct * 32 + m) * 128 + kk + kg * 8);
                acc[ct] = __builtin_amdgcn_mfma_f32_32x32x16_bf16(ah.v, bl, acc[ct], 0, 0, 0);
                acc[ct] = __builtin_amdgcn_mfma_f32_32x32x16_bf16(al.v, bh, acc[ct], 0, 0, 0);
            }
        }
    }

    if (typ < 2) {
        u16* H = (typ == 0) ? Qh : Kh;
        u16* L = (typ == 0) ? Ql : Kl;
#pragma unroll
        for (int ct = 0; ct < 4; ct++) {
            int col = ct * 32 + m;
#pragma unroll
            for (int r = 0; r < 16; r++) {
                int row = (r & 3) + 8 * (r >> 2) + 4 * kg;
                float vv = acc[ct][r];
                u16 hb = f2b_rne(vv);
                int idx = (r0 + row) * 128 + col;
                H[idx] = hb;
                L[idx] = f2b_rne(vv - b2f(hb));
            }
        }
    } else {
        int b = r0 >> 11;
        int sbase = r0 & 2047;
#pragma unroll
        for (int ct = 0; ct < 4; ct++) {
            int col = ct * 32 + m;
#pragma unroll
            for (int rg = 0; rg < 4; rg++) {
                int rowb = rg * 8 + 4 * kg;      // rows rowb..rowb+3 contiguous in s
                BF8 pk;
#pragma unroll
                for (int q = 0; q < 4; q++) pk.s[q] = f2b_rne(acc[ct][rg * 4 + q]);
                u32x4 tmp = pk.q;
                // store 4 bf16 = 8B
                *(u32*)(VT + (b * 128 + col) * 2048 + sbase + rowb)     = tmp[0];
                *(u32*)(VT + (b * 128 + col) * 2048 + sbase + rowb + 2) = tmp[1];
            }
        }
    }
}

// ---------------------------------------------------------------------------
// fused attention: one wave = 32 queries of one (b,h). Two passes over keys:
//   pass1: scores (3-MFMA hi/lo split) -> exact per-row max (log2 domain)
//   pass2: recompute scores, exp2, probs -> LDS (C->A relayout), PV MFMA
// No __syncthreads in the key loop (per-wave private LDS prob buffer).
// grid: 4b * 7h * 16 qblocks = 448, block 256.
// ---------------------------------------------------------------------------
__global__ __launch_bounds__(256) void attn_kernel(
    const u16* Qh, const u16* Ql, const u16* Kh, const u16* Kl,
    const u16* VT, const float* bias2, u16* AO)
{
    __shared__ u16 pbuf[4][32][72];   // 72-ushort stride: 16B-aligned rows, depads banks
    __shared__ float lsm[4][32];

    int bid = blockIdx.x;
    int qb = bid & 15;
    int h  = (bid >> 4) % 7;
    int b  = bid / (16 * 7);
    int wave = threadIdx.x >> 6, lane = threadIdx.x & 63;
    int m = lane & 31, kg = lane >> 5;
    int krow = lane >> 4;            // PV A/B k-group (0..3)

    int qrow = b * 2048 + qb * 128 + wave * 32;     // global row of query 0 of this wave
    bf16x8 qfh = ld_bf8(Qh + (qrow + m) * 128 + h * 16 + kg * 8);
    bf16x8 qfl = ld_bf8(Ql + (qrow + m) * 128 + h * 16 + kg * 8);

    const u16* kbh = Kh + b * 2048 * 128 + h * 16 + kg * 8;
    const u16* kbl = Kl + b * 2048 * 128 + h * 16 + kg * 8;
    const float* bias_b = bias2 + b * 2048;

    const float scale2 = (float)(1.4426950408889634 / 11.313708498984761); // log2(e)/sqrt(128)

    // ---- pass 1: row maxima ----
    float mloc[16];
#pragma unroll
    for (int r = 0; r < 16; r++) mloc[r] = -3.0e38f;

    for (int t = 0; t < 2048; t += 32) {
        bf16x8 kh8 = ld_bf8(kbh + (t + m) * 128);
        bf16x8 kl8 = ld_bf8(kbl + (t + m) * 128);
        f32x16 sc = __builtin_amdgcn_mfma_f32_32x32x16_bf16(qfl, kh8, zero16(), 0, 0, 0);
        sc = __builtin_amdgcn_mfma_f32_32x32x16_bf16(qfh, kl8, sc, 0, 0, 0);
        sc = __builtin_amdgcn_mfma_f32_32x32x16_bf16(qfh, kh8, sc, 0, 0, 0);
        float bl = bias_b[t + m];
#pragma unroll
        for (int r = 0; r < 16; r++) {
            float s2 = fmaf(sc[r], scale2, bl);
            mloc[r] = fmaxf(mloc[r], s2);
        }
    }
    // reduce across the 32-lane half (rows live within one half)
#pragma unroll
    for (int d = 1; d < 32; d <<= 1) {
#pragma unroll
        for (int r = 0; r < 16; r++)
            mloc[r] = fmaxf(mloc[r], __shfl_xor(mloc[r], d, 64));
    }

    // ---- pass 2: exp + PV ----
    float lacc[16];
#pragma unroll
    for (int r = 0; r < 16; r++) lacc[r] = 0.f;
    f32x4 o0 = zero4(), o1 = zero4();

    const u16* vtb = VT + (b * 128 + h * 16 + (lane & 15)) * 2048;

    for (int t = 0; t < 2048; t += 64) {
#pragma unroll
        for (int sub = 0; sub < 2; sub++) {
            int k0 = t + sub * 32;
            bf16x8 kh8 = ld_bf8(kbh + (k0 + m) * 128);
            bf16x8 kl8 = ld_bf8(kbl + (k0 + m) * 128);
            f32x16 sc = __builtin_amdgcn_mfma_f32_32x32x16_bf16(qfl, kh8, zero16(), 0, 0, 0);
            sc = __builtin_amdgcn_mfma_f32_32x32x16_bf16(qfh, kl8, sc, 0, 0, 0);
            sc = __builtin_amdgcn_mfma_f32_32x32x16_bf16(qfh, kh8, sc, 0, 0, 0);
            float bl = bias_b[k0 + m];
#pragma unroll
            for (int r = 0; r < 16; r++) {
                float s2 = fmaf(sc[r], scale2, bl);
                float e = __builtin_amdgcn_exp2f(s2 - mloc[r]);
                lacc[r] += e;
                u32 eb = __builtin_bit_cast(u32, e);
                int row = (r & 3) + 8 * (r >> 2) + 4 * kg;
                pbuf[wave][row][sub * 32 + m] = (u16)(eb >> 16);  // truncate to bf16
            }
        }
        // PV over the 64 keys just written (same-wave DS ordering is safe)
#pragma unroll
        for (int kc = 0; kc < 2; kc++) {
            bf16x8 vf = ld_bf8(vtb + t + kc * 32 + krow * 8);
            bf16x8 p0 = *(const bf16x8*)&pbuf[wave][lane & 15][kc * 32 + krow * 8];
            bf16x8 p1 = *(const bf16x8*)&pbuf[wave][(lane & 15) + 16][kc * 32 + krow * 8];
            o0 = __builtin_amdgcn_mfma_f32_16x16x32_bf16(p0, vf, o0, 0, 0, 0);
            o1 = __builtin_amdgcn_mfma_f32_16x16x32_bf16(p1, vf, o1, 0, 0, 0);
        }
    }

    // reduce l across half, broadcast via LDS
#pragma unroll
    for (int d = 1; d < 32; d <<= 1) {
#pragma unroll
        for (int r = 0; r < 16; r++)
            lacc[r] += __shfl_xor(lacc[r], d, 64);
    }
    if (m == 0) {
#pragma unroll
        for (int r = 0; r < 16; r++) {
            int row = (r & 3) + 8 * (r >> 2) + 4 * kg;
            lsm[wave][row] = lacc[r];
        }
    }
    __syncthreads();

    // epilogue: normalize, write bf16 attn output with buggy head->slot map
    // head h -> slot: h0->0, h1->{1,2}, h>=2 -> h+1   (head 7 never computed)
    int d16 = lane & 15;
    int slot0 = (h == 0) ? 0 : h + 1;
#pragma unroll
    for (int half = 0; half < 2; half++) {
        f32x4 ov = half ? o1 : o0;
#pragma unroll
        for (int r = 0; r < 4; r++) {
            int ql_ = half * 16 + krow * 4 + r;
            float rin = __builtin_amdgcn_rcpf(lsm[wave][ql_]);
            u16 vb = f2b_rne(ov[r] * rin);
            int orow = qrow + ql_;
            AO[orow * 128 + slot0 * 16 + d16] = vb;
            if (h == 1) AO[orow * 128 + 16 + d16] = vb;
        }
    }
}

// ---------------------------------------------------------------------------
// final linear: out = AO(bf16) @ lin_w^T + lin_b, fp32 out
// ---------------------------------------------------------------------------
__global__ __launch_bounds__(256) void fin_kernel(
    const u16* AO, const u16* lwb, const float* lb, float* out)
{
    int wave = threadIdx.x >> 6, lane = threadIdx.x & 63;
    int m = lane & 31, kg = lane >> 5;
    int r0 = blockIdx.x * 128 + wave * 32;

    f32x16 acc[4];
#pragma unroll
    for (int ct = 0; ct < 4; ct++) acc[ct] = zero16();

    for (int kk = 0; kk < 128; kk += 16) {
        bf16x8 af = ld_bf8(AO + (r0 + m) * 128 + kk + kg * 8);
#pragma unroll
        for (int ct = 0; ct < 4; ct++) {
            bf16x8 bfr = ld_bf8(lwb + (ct * 32 + m) * 128 + kk + kg * 8);
            acc[ct] = __builtin_amdgcn_mfma_f32_32x32x16_bf16(af, bfr, acc[ct], 0, 0, 0);
        }
    }
#pragma unroll
    for (int ct = 0; ct < 4; ct++) {
        int col = ct * 32 + m;
        float bias = lb[col];
#pragma unroll
        for (int r = 0; r < 16; r++) {
            int row = (r & 3) + 8 * (r >> 2) + 4 * kg;
            out[(r0 + row) * 128 + col] = acc[ct][r] + bias;
        }
    }
}

// ---------------------------------------------------------------------------
extern "C" void kernel_launch(void* const* d_in, const int* in_sizes, int n_in,
                              void* d_out, int out_size, void* d_ws, size_t ws_size,
                              hipStream_t stream)
{
    const float* x    = (const float*)d_in[0];
    const int*   mask = (const int*)d_in[1];
    const float* wq   = (const float*)d_in[2];
    const float* wk   = (const float*)d_in[3];
    const float* wv   = (const float*)d_in[4];
    const float* lw   = (const float*)d_in[5];
    const float* lb   = (const float*)d_in[6];
    float* out = (float*)d_out;

    char* ws = (char*)d_ws;
    u16*   wq_th = (u16*)(ws + 0);
    u16*   wq_tl = (u16*)(ws + 32768);
    u16*   wk_th = (u16*)(ws + 65536);
    u16*   wk_tl = (u16*)(ws + 98304);
    u16*   wv_t  = (u16*)(ws + 131072);
    u16*   lwb   = (u16*)(ws + 163840);
    float* bias2 = (float*)(ws + 196608);
    u16*   Qh    = (u16*)(ws + 229376);
    u16*   Ql    = (u16*)(ws + 229376 + 2097152);
    u16*   Kh    = (u16*)(ws + 229376 + 2 * 2097152);
    u16*   Kl    = (u16*)(ws + 229376 + 3 * 2097152);
    u16*   VT    = (u16*)(ws + 229376 + 4 * 2097152);
    u16*   AO    = (u16*)(ws + 229376 + 5 * 2097152);

    prep_kernel<<<64, 256, 0, stream>>>(wq, wk, wv, lw, mask,
                                        wq_th, wq_tl, wk_th, wk_tl, wv_t, lwb, bias2);
    proj_kernel<<<dim3(64, 3), 256, 0, stream>>>(x, wq_th, wq_tl, wk_th, wk_tl, wv_t,
                                                 Qh, Ql, Kh, Kl, VT);
    attn_kernel<<<448, 256, 0, stream>>>(Qh, Ql, Kh, Kl, VT, bias2, AO);
    fin_kernel<<<64, 256, 0, stream>>>(AO, lwb, lb, out);
}

// Round 2
// 137.510 us; speedup vs baseline: 1.4800x; 1.4800x over previous
//
#include <hip/hip_runtime.h>
#include <stdint.h>

typedef unsigned short u16;
typedef unsigned int   u32;
typedef float   f32x4  __attribute__((ext_vector_type(4)));
typedef float   f32x16 __attribute__((ext_vector_type(16)));
typedef __bf16  bf16x8 __attribute__((ext_vector_type(8)));
typedef u32     u32x4  __attribute__((ext_vector_type(4)));

union BF8 { bf16x8 v; u16 s[8]; u32x4 q; };

__device__ __forceinline__ u16 f2b_rne(float f) {
    u32 u = __builtin_bit_cast(u32, f);
    u32 r = u + 0x7FFFu + ((u >> 16) & 1u);
    return (u16)(r >> 16);
}
__device__ __forceinline__ u16 f2b_trunc(float f) {
    return (u16)(__builtin_bit_cast(u32, f) >> 16);
}
__device__ __forceinline__ float b2f(u16 h) {
    u32 u = ((u32)h) << 16;
    return __builtin_bit_cast(float, u);
}
__device__ __forceinline__ bf16x8 ld_bf8(const u16* p) {
    BF8 t; t.q = *(const u32x4*)p; return t.v;
}
__device__ __forceinline__ f32x16 zero16() {
    f32x16 z;
#pragma unroll
    for (int i = 0; i < 16; i++) z[i] = 0.f;
    return z;
}
__device__ __forceinline__ f32x4 zero4() {
    f32x4 z;
#pragma unroll
    for (int i = 0; i < 4; i++) z[i] = 0.f;
    return z;
}

#define SCALE2 0.1275312959479341f   /* log2(e)/sqrt(128) */

// ---------------------------------------------------------------------------
// prep: transpose + hi/lo split Wq/Wk, transpose Wv, bf16 lin_w, mask -> bias2
// (bias2 in log2 domain: -1000*log2(e))
// ---------------------------------------------------------------------------
__global__ __launch_bounds__(256) void prep_kernel(
    const float* wq, const float* wk, const float* wv,
    const float* lw, const int* mask,
    u16* wq_th, u16* wq_tl, u16* wk_th, u16* wk_tl,
    u16* wv_t, u16* lwb, float* bias2)
{
    int t = blockIdx.x * 256 + threadIdx.x;
    if (t < 16384) {
        int n = t >> 7, i = t & 127;
        float q = wq[i * 128 + n];
        float k = wk[i * 128 + n];
        float v = wv[i * 128 + n];
        u16 qh = f2b_rne(q); wq_th[t] = qh; wq_tl[t] = f2b_trunc(q - b2f(qh));
        u16 kh = f2b_rne(k); wk_th[t] = kh; wk_tl[t] = f2b_trunc(k - b2f(kh));
        wv_t[t] = f2b_rne(v);
        lwb[t] = f2b_rne(lw[t]);
    }
    if (t < 8192)
        bias2[t] = (mask[t] == 0) ? -1442.6950408889634f : 0.0f;
}

// ---------------------------------------------------------------------------
// projection: grid (256, 3) blocks of 256 thr; block = 32 rows, wave = one
// 32-col tile. Q/K written hi/lo head-packed [b][h(8)][s][16] (Q pre-scaled
// by log2e/sqrt(128)); V written transposed VT[b*128+n][s].
// ---------------------------------------------------------------------------
__global__ __launch_bounds__(256) void proj_kernel(
    const float* x,
    const u16* wq_th, const u16* wq_tl,
    const u16* wk_th, const u16* wk_tl,
    const u16* wv_t,
    u16* Qph, u16* Qpl, u16* Kph, u16* Kpl, u16* VT)
{
    int typ  = blockIdx.y;                 // 0=Q 1=K 2=V
    int ct   = threadIdx.x >> 6;
    int lane = threadIdx.x & 63;
    int m = lane & 31, kg = lane >> 5;
    int r0 = blockIdx.x * 32;

    const u16* wh = (typ == 0) ? wq_th : (typ == 1) ? wk_th : wv_t;
    const u16* wl = (typ == 0) ? wq_tl : wk_tl;

    f32x16 acc = zero16();

    for (int kk = 0; kk < 128; kk += 16) {
        const float* xp = x + (r0 + m) * 128 + kk + kg * 8;
        f32x4 x0 = *(const f32x4*)xp;
        f32x4 x1 = *(const f32x4*)(xp + 4);
        BF8 ah, al;
#pragma unroll
        for (int j = 0; j < 4; j++) {
            u16 hb = f2b_trunc(x0[j]);
            ah.s[j] = hb; al.s[j] = f2b_trunc(x0[j] - b2f(hb));
            u16 hb2 = f2b_trunc(x1[j]);
            ah.s[4 + j] = hb2; al.s[4 + j] = f2b_trunc(x1[j] - b2f(hb2));
        }
        const u16* bp = wh + (ct * 32 + m) * 128 + kk + kg * 8;
        bf16x8 bh = ld_bf8(bp);
        acc = __builtin_amdgcn_mfma_f32_32x32x16_bf16(ah.v, bh, acc, 0, 0, 0);
        if (typ < 2) {
            bf16x8 bl8 = ld_bf8(wl + (ct * 32 + m) * 128 + kk + kg * 8);
            acc = __builtin_amdgcn_mfma_f32_32x32x16_bf16(ah.v, bl8, acc, 0, 0, 0);
            acc = __builtin_amdgcn_mfma_f32_32x32x16_bf16(al.v, bh, acc, 0, 0, 0);
        }
    }

    int col = ct * 32 + m;
    int b = r0 >> 11, sl = r0 & 2047;
    if (typ < 2) {
        u16* H = typ ? Kph : Qph;
        u16* L = typ ? Kpl : Qpl;
        int hh = col >> 4, d = col & 15;
        float scl = (typ == 0) ? SCALE2 : 1.0f;
        size_t hb_off = (size_t)(b * 8 + hh) * 2048 * 16 + d;
#pragma unroll
        for (int r = 0; r < 16; r++) {
            int row = (r & 3) + 8 * (r >> 2) + 4 * kg;
            float v = acc[r] * scl;
            u16 hi = f2b_trunc(v);
            size_t idx = hb_off + (size_t)(sl + row) * 16;
            H[idx] = hi;
            L[idx] = f2b_trunc(v - b2f(hi));
        }
    } else {
#pragma unroll
        for (int rg = 0; rg < 4; rg++) {
            int rowb = rg * 8 + 4 * kg;
            BF8 pk;
#pragma unroll
            for (int q = 0; q < 4; q++) pk.s[q] = f2b_rne(acc[rg * 4 + q]);
            u32x4 tmp = pk.q;
            *(u32*)(VT + (size_t)(b * 128 + col) * 2048 + sl + rowb)     = tmp[0];
            *(u32*)(VT + (size_t)(b * 128 + col) * 2048 + sl + rowb + 2) = tmp[1];
        }
    }
}

// ---------------------------------------------------------------------------
// fused attention, key-split: block = 4 waves, each wave = same 32 queries x
// its own 512-key range. Pass1: approx scores (Qh*Kh, 1 MFMA) -> per-row max,
// combined across waves in LDS. Pass2: exact scores (3 MFMA), exp2, probs ->
// per-wave LDS tile -> PV MFMA + ones-column MFMA for the row-sum l.
// Final: cross-wave combine of (o, l) in LDS, normalize, write AO.
// grid: bid = (b*7+h) + 28*qt  (same (b,h) lands on <=2 XCDs, balanced).
// ---------------------------------------------------------------------------
__global__ __launch_bounds__(256, 6) void attn_kernel(
    const u16* Qph, const u16* Qpl, const u16* Kph, const u16* Kpl,
    const u16* VT, const float* bias2, u16* AO)
{
    __shared__ u16 pbuf[4][32][40];      // per-wave P tile, stride 40 (80B, 16B-aligned, conflict-lite)
    __shared__ float lsmax[32][4];
    __shared__ float obuf[4][16][32];    // [wave][d][q]
    __shared__ float lbuf[4][32];        // [wave][q]

    int bid = blockIdx.x;
    int bh = bid % 28;
    int qt = bid / 28;
    int b = bh / 7, h = bh % 7;
    int wave = threadIdx.x >> 6, lane = threadIdx.x & 63;
    int m = lane & 31, kg = lane >> 5;
    int qs = qt * 32;

    const u16* qoff = (const u16*)0;
    size_t headoff = (size_t)(b * 8 + h) * 2048 * 16;
    bf16x8 qfh = ld_bf8(Qph + headoff + (size_t)(qs + m) * 16 + kg * 8);
    bf16x8 qfl = ld_bf8(Qpl + headoff + (size_t)(qs + m) * 16 + kg * 8);
    (void)qoff;

    const u16* kbh = Kph + headoff;
    const u16* kbl = Kpl + headoff;
    const float* bias_b = bias2 + b * 2048;

    int t0 = wave * 512;

    // ---- pass 1: approximate row maxima (overflow guard; underestimate <~3) ----
    float mloc[16];
#pragma unroll
    for (int r = 0; r < 16; r++) mloc[r] = -3.0e38f;

    for (int t = t0; t < t0 + 512; t += 32) {
        bf16x8 kf = ld_bf8(kbh + (t + m) * 16 + kg * 8);
        float bl = bias_b[t + m];
        f32x16 sc = __builtin_amdgcn_mfma_f32_32x32x16_bf16(qfh, kf, zero16(), 0, 0, 0);
#pragma unroll
        for (int r = 0; r < 16; r++)
            mloc[r] = fmaxf(mloc[r], sc[r] + bl);
    }
#pragma unroll
    for (int d = 1; d < 32; d <<= 1) {
#pragma unroll
        for (int r = 0; r < 16; r++)
            mloc[r] = fmaxf(mloc[r], __shfl_xor(mloc[r], d, 64));
    }
    if (m == 0) {
#pragma unroll
        for (int r = 0; r < 16; r++)
            lsmax[(r & 3) + 8 * (r >> 2) + 4 * kg][wave] = mloc[r];
    }
    __syncthreads();
    float mrow[16];
#pragma unroll
    for (int r = 0; r < 16; r++) {
        int row = (r & 3) + 8 * (r >> 2) + 4 * kg;
        f32x4 mv = *(const f32x4*)&lsmax[row][0];
        mrow[r] = fmaxf(fmaxf(mv[0], mv[1]), fmaxf(mv[2], mv[3]));
    }

    // ---- pass 2 ----
    f32x4 o0 = zero4(), o1 = zero4(), l0 = zero4(), l1 = zero4();
    BF8 onesu;
#pragma unroll
    for (int j = 0; j < 8; j++) onesu.s[j] = 0x3F80;
    bf16x8 ones = onesu.v;

    int q16 = lane & 15, krow = lane >> 4;
    const u16* vtb = VT + (size_t)(b * 128 + h * 16 + q16) * 2048;

    for (int t = t0; t < t0 + 512; t += 32) {
        bf16x8 kh8 = ld_bf8(kbh + (t + m) * 16 + kg * 8);
        bf16x8 kl8 = ld_bf8(kbl + (t + m) * 16 + kg * 8);
        float bl = bias_b[t + m];
        f32x16 sc = __builtin_amdgcn_mfma_f32_32x32x16_bf16(qfl, kh8, zero16(), 0, 0, 0);
        sc = __builtin_amdgcn_mfma_f32_32x32x16_bf16(qfh, kl8, sc, 0, 0, 0);
        sc = __builtin_amdgcn_mfma_f32_32x32x16_bf16(qfh, kh8, sc, 0, 0, 0);
#pragma unroll
        for (int r = 0; r < 16; r++) {
            float e = __builtin_amdgcn_exp2f(sc[r] + (bl - mrow[r]));
            int row = (r & 3) + 8 * (r >> 2) + 4 * kg;
            pbuf[wave][row][m] = f2b_trunc(e);
        }
        bf16x8 vf = ld_bf8(vtb + t + krow * 8);
        bf16x8 p0 = *(const bf16x8*)&pbuf[wave][q16][krow * 8];
        bf16x8 p1 = *(const bf16x8*)&pbuf[wave][q16 + 16][krow * 8];
        o0 = __builtin_amdgcn_mfma_f32_16x16x32_bf16(p0, vf, o0, 0, 0, 0);
        o1 = __builtin_amdgcn_mfma_f32_16x16x32_bf16(p1, vf, o1, 0, 0, 0);
        l0 = __builtin_amdgcn_mfma_f32_16x16x32_bf16(p0, ones, l0, 0, 0, 0);
        l1 = __builtin_amdgcn_mfma_f32_16x16x32_bf16(p1, ones, l1, 0, 0, 0);
    }

    // ---- cross-wave combine ----
    int q0 = krow * 4;
    *(f32x4*)&obuf[wave][q16][q0]      = o0;
    *(f32x4*)&obuf[wave][q16][q0 + 16] = o1;
    if (q16 == 0) {
        *(f32x4*)&lbuf[wave][q0]      = l0;
        *(f32x4*)&lbuf[wave][q0 + 16] = l1;
    }
    __syncthreads();

    int d = threadIdx.x & 15, q = threadIdx.x >> 4;
    int slot0 = (h == 0) ? 0 : h + 1;
#pragma unroll
    for (int hf = 0; hf < 2; hf++) {
        int qq = q + hf * 16;
        float os = obuf[0][d][qq] + obuf[1][d][qq] + obuf[2][d][qq] + obuf[3][d][qq];
        float ls = lbuf[0][qq] + lbuf[1][qq] + lbuf[2][qq] + lbuf[3][qq];
        u16 vb = f2b_rne(os * __builtin_amdgcn_rcpf(ls));
        int orow = b * 2048 + qs + qq;
        AO[orow * 128 + slot0 * 16 + d] = vb;
        if (h == 1) AO[orow * 128 + 16 + d] = vb;
    }
}

// ---------------------------------------------------------------------------
// final linear: out = AO(bf16) @ lin_w^T + lin_b, fp32 out.
// grid 256 blocks of 32 rows; wave = one 32-col tile.
// ---------------------------------------------------------------------------
__global__ __launch_bounds__(256) void fin_kernel(
    const u16* AO, const u16* lwb, const float* lb, float* out)
{
    int ct   = threadIdx.x >> 6;
    int lane = threadIdx.x & 63;
    int m = lane & 31, kg = lane >> 5;
    int r0 = blockIdx.x * 32;

    f32x16 acc = zero16();
    for (int kk = 0; kk < 128; kk += 16) {
        bf16x8 af  = ld_bf8(AO + (r0 + m) * 128 + kk + kg * 8);
        bf16x8 bfr = ld_bf8(lwb + (ct * 32 + m) * 128 + kk + kg * 8);
        acc = __builtin_amdgcn_mfma_f32_32x32x16_bf16(af, bfr, acc, 0, 0, 0);
    }
    int col = ct * 32 + m;
    float bias = lb[col];
#pragma unroll
    for (int r = 0; r < 16; r++) {
        int row = (r & 3) + 8 * (r >> 2) + 4 * kg;
        out[(r0 + row) * 128 + col] = acc[r] + bias;
    }
}

// ---------------------------------------------------------------------------
extern "C" void kernel_launch(void* const* d_in, const int* in_sizes, int n_in,
                              void* d_out, int out_size, void* d_ws, size_t ws_size,
                              hipStream_t stream)
{
    const float* x    = (const float*)d_in[0];
    const int*   mask = (const int*)d_in[1];
    const float* wq   = (const float*)d_in[2];
    const float* wk   = (const float*)d_in[3];
    const float* wv   = (const float*)d_in[4];
    const float* lw   = (const float*)d_in[5];
    const float* lb   = (const float*)d_in[6];
    float* out = (float*)d_out;

    char* ws = (char*)d_ws;
    u16*   wq_th = (u16*)(ws + 0);
    u16*   wq_tl = (u16*)(ws + 32768);
    u16*   wk_th = (u16*)(ws + 65536);
    u16*   wk_tl = (u16*)(ws + 98304);
    u16*   wv_t  = (u16*)(ws + 131072);
    u16*   lwb   = (u16*)(ws + 163840);
    float* bias2 = (float*)(ws + 196608);
    u16*   Qph   = (u16*)(ws + 229376);
    u16*   Qpl   = (u16*)(ws + 229376 + 1 * 2097152);
    u16*   Kph   = (u16*)(ws + 229376 + 2 * 2097152);
    u16*   Kpl   = (u16*)(ws + 229376 + 3 * 2097152);
    u16*   VT    = (u16*)(ws + 229376 + 4 * 2097152);
    u16*   AO    = (u16*)(ws + 229376 + 5 * 2097152);

    prep_kernel<<<64, 256, 0, stream>>>(wq, wk, wv, lw, mask,
                                        wq_th, wq_tl, wk_th, wk_tl, wv_t, lwb, bias2);
    proj_kernel<<<dim3(256, 3), 256, 0, stream>>>(x, wq_th, wq_tl, wk_th, wk_tl, wv_t,
                                                  Qph, Qpl, Kph, Kpl, VT);
    attn_kernel<<<1792, 256, 0, stream>>>(Qph, Qpl, Kph, Kpl, VT, bias2, AO);
    fin_kernel<<<256, 256, 0, stream>>>(AO, lwb, lb, out);
}

// Round 4
// 125.861 us; speedup vs baseline: 1.6170x; 1.0925x over previous
//
#include <hip/hip_runtime.h>
#include <stdint.h>

typedef unsigned short u16;
typedef unsigned int   u32;
typedef float   f32x4  __attribute__((ext_vector_type(4)));
typedef float   f32x16 __attribute__((ext_vector_type(16)));
typedef __bf16  bf16x8 __attribute__((ext_vector_type(8)));
typedef u32     u32x4  __attribute__((ext_vector_type(4)));
typedef u32     u32x2  __attribute__((ext_vector_type(2)));

union BF8 { bf16x8 v; u16 s[8]; u32x4 q; };

__device__ __forceinline__ u16 f2b_rne(float f) {
    u32 u = __builtin_bit_cast(u32, f);
    u32 r = u + 0x7FFFu + ((u >> 16) & 1u);
    return (u16)(r >> 16);
}
__device__ __forceinline__ u16 f2b_trunc(float f) {
    return (u16)(__builtin_bit_cast(u32, f) >> 16);
}
__device__ __forceinline__ float b2f(u16 h) {
    u32 u = ((u32)h) << 16;
    return __builtin_bit_cast(float, u);
}
__device__ __forceinline__ bf16x8 ld_bf8(const u16* p) {
    BF8 t; t.q = *(const u32x4*)p; return t.v;
}
__device__ __forceinline__ f32x16 zero16() {
    f32x16 z;
#pragma unroll
    for (int i = 0; i < 16; i++) z[i] = 0.f;
    return z;
}
__device__ __forceinline__ f32x4 zero4() {
    f32x4 z;
#pragma unroll
    for (int i = 0; i < 4; i++) z[i] = 0.f;
    return z;
}

#define SCALE2 0.1275312959479341f        /* log2(e)/sqrt(128) */
#define MBIAS2 -1442.6950408889634f       /* -1000*log2(e) */

// ---------------------------------------------------------------------------
// projection: on-the-fly W column reads (coalesced per-lane, L1-hot).
// Q/K written hi/lo head-packed [b][h][s][16], Q pre-scaled by log2e/sqrt(128).
// V written transposed VT[b*128+n][s] (REAL values — reference's mask is a
// soft bias, masked keys can legitimately carry weight). grid (256,3) x 256.
// ---------------------------------------------------------------------------
__global__ __launch_bounds__(256) void proj_kernel(
    const float* __restrict__ x, const float* __restrict__ wq,
    const float* __restrict__ wk, const float* __restrict__ wv,
    u16* Qph, u16* Qpl, u16* Kph, u16* Kpl, u16* VT)
{
    int typ  = blockIdx.y;                 // 0=Q 1=K 2=V
    int ct   = threadIdx.x >> 6;
    int lane = threadIdx.x & 63;
    int m = lane & 31, kg = lane >> 5;
    int r0 = blockIdx.x * 32;
    int c = ct * 32 + m;

    const float* wp = (typ == 0) ? wq : (typ == 1) ? wk : wv;

    f32x16 acc = zero16();
    for (int kk = 0; kk < 128; kk += 16) {
        const float* xp = x + (size_t)(r0 + m) * 128 + kk + kg * 8;
        f32x4 x0 = *(const f32x4*)xp;
        f32x4 x1 = *(const f32x4*)(xp + 4);
        BF8 ah, al;
#pragma unroll
        for (int j = 0; j < 4; j++) {
            u16 hb = f2b_trunc(x0[j]);
            ah.s[j] = hb; al.s[j] = f2b_trunc(x0[j] - b2f(hb));
            u16 hb2 = f2b_trunc(x1[j]);
            ah.s[4 + j] = hb2; al.s[4 + j] = f2b_trunc(x1[j] - b2f(hb2));
        }
        const float* wcol = wp + (size_t)(kk + kg * 8) * 128 + c;
        if (typ < 2) {
            BF8 bh, bl_;
#pragma unroll
            for (int j = 0; j < 8; j++) {
                float w = wcol[(size_t)j * 128];
                u16 hb = f2b_trunc(w);
                bh.s[j] = hb; bl_.s[j] = f2b_trunc(w - b2f(hb));
            }
            acc = __builtin_amdgcn_mfma_f32_32x32x16_bf16(ah.v, bh.v, acc, 0, 0, 0);
            acc = __builtin_amdgcn_mfma_f32_32x32x16_bf16(ah.v, bl_.v, acc, 0, 0, 0);
            acc = __builtin_amdgcn_mfma_f32_32x32x16_bf16(al.v, bh.v, acc, 0, 0, 0);
        } else {
            BF8 bh;
#pragma unroll
            for (int j = 0; j < 8; j++) bh.s[j] = f2b_rne(wcol[(size_t)j * 128]);
            acc = __builtin_amdgcn_mfma_f32_32x32x16_bf16(ah.v, bh.v, acc, 0, 0, 0);
        }
    }

    int b = r0 >> 11, sl = r0 & 2047;
    if (typ < 2) {
        u16* H = typ ? Kph : Qph;
        u16* L = typ ? Kpl : Qpl;
        int hh = c >> 4, d = c & 15;
        if (hh == 7) return;                      // head 7 never consumed
        float scl = (typ == 0) ? SCALE2 : 1.0f;
        size_t hb_off = (size_t)(b * 8 + hh) * 2048 * 16 + d;
#pragma unroll
        for (int r = 0; r < 16; r++) {
            int row = (r & 3) + 8 * (r >> 2) + 4 * kg;
            float v = acc[r] * scl;
            u16 hi = f2b_trunc(v);
            size_t idx = hb_off + (size_t)(sl + row) * 16;
            H[idx] = hi;
            L[idx] = f2b_trunc(v - b2f(hi));
        }
    } else {
        if ((c >> 4) == 7) return;
#pragma unroll
        for (int rg = 0; rg < 4; rg++) {
            int rowb = rg * 8 + 4 * kg;
            BF8 pk;
#pragma unroll
            for (int q = 0; q < 4; q++) pk.s[q] = f2b_rne(acc[rg * 4 + q]);
            u32x4 tmp = pk.q;
            *(u32*)(VT + (size_t)(b * 128 + c) * 2048 + sl + rowb)     = tmp[0];
            *(u32*)(VT + (size_t)(b * 128 + c) * 2048 + sl + rowb + 2) = tmp[1];
        }
    }
}

// ---------------------------------------------------------------------------
// fused attention, S^T orientation (lane = query, keys in regs). The soft
// mask bias (0 / -1442.7, log2 domain) is staged in LDS pre-permuted into
// MFMA C-layout and fed as the C operand of the first score MFMA in BOTH
// passes — so mrow tracks the BIASED max (e<=2^~1, l>=2^~-1: no under/
// overflow, and faithful to the reference's soft masking; V stays real,
// l = ones-MFMA over full P). Block = 4 waves x 512-key split, grid 1792.
// ---------------------------------------------------------------------------
__global__ __launch_bounds__(256, 6) void attn_kernel(
    const u16* __restrict__ Qph, const u16* __restrict__ Qpl,
    const u16* __restrict__ Kph, const u16* __restrict__ Kpl,
    const u16* __restrict__ VT, const int* __restrict__ mask, u16* AO)
{
    __shared__ char smem[18944];
    u16*   pbuf  = (u16*)smem;               // [4][32][40] u16 = 10240 B
    float* biasC = (float*)(smem + 10240);   // [64 tiles][2 kg][16 reg] = 8192 B
    float* lsmax = (float*)(smem + 18432);   // [32][4] = 512 B
    float* obuf  = (float*)smem;             // [4][16][32] f32, aliases pbuf
    float* lbuf  = (float*)(smem + 8192);    // [4][32] f32, aliases pbuf

    int bid = blockIdx.x;
    int bh = bid % 28;
    int qt = bid / 28;
    int b = bh / 7, h = bh % 7;
    int wave = threadIdx.x >> 6, lane = threadIdx.x & 63;
    int m = lane & 31, kg = lane >> 5;
    int qs = qt * 32;

    // ---- prologue: bias table in MFMA C-layout: entry e=(tile*32+kg*16+r)
    //      -> key tile*32 + (r&3)+8*(r>>2)+4*kg ----
    {
        int e0 = threadIdx.x * 8;
        const int* mp = mask + b * 2048;
        float v[8];
#pragma unroll
        for (int j = 0; j < 8; j++) {
            int e = e0 + j;
            int ti = e >> 5, kgg = (e >> 4) & 1, r = e & 15;
            int key = ti * 32 + (r & 3) + 8 * (r >> 2) + 4 * kgg;
            v[j] = (mp[key] != 0) ? 0.0f : MBIAS2;
        }
        *(f32x4*)(biasC + e0)     = *(const f32x4*)&v[0];
        *(f32x4*)(biasC + e0 + 4) = *(const f32x4*)&v[4];
    }
    __syncthreads();

    size_t headoff = (size_t)(b * 8 + h) * 2048 * 16;
    bf16x8 qfh = ld_bf8(Qph + headoff + (size_t)(qs + m) * 16 + kg * 8);
    bf16x8 qfl = ld_bf8(Qpl + headoff + (size_t)(qs + m) * 16 + kg * 8);
    const u16* kbh = Kph + headoff;
    const u16* kbl = Kpl + headoff;

    int t0 = wave * 512;

    // ---- pass 1: per-query max of approx biased scores (K hi x Q hi + bias) ----
    float mloc = -3.0e38f;
    for (int t = t0; t < t0 + 512; t += 32) {
        bf16x8 kh8 = ld_bf8(kbh + (size_t)(t + m) * 16 + kg * 8);
        f32x16 ci = *(const f32x16*)(biasC + (t >> 5) * 32 + kg * 16);
        f32x16 sc = __builtin_amdgcn_mfma_f32_32x32x16_bf16(kh8, qfh, ci, 0, 0, 0);
#pragma unroll
        for (int r = 0; r < 16; r++) mloc = fmaxf(mloc, sc[r]);
    }
    mloc = fmaxf(mloc, __shfl_xor(mloc, 32, 64));
    if (kg == 0) lsmax[m * 4 + wave] = mloc;
    __syncthreads();
    f32x4 mv = *(const f32x4*)(lsmax + m * 4);
    float mrow = fmaxf(fmaxf(mv[0], mv[1]), fmaxf(mv[2], mv[3]));  // per-lane (query m)

    // ---- pass 2: exact biased scores -> exp2 -> P tile -> PV + ones-sum ----
    f32x4 o0 = zero4(), o1 = zero4(), l0 = zero4(), l1 = zero4();
    BF8 onesu;
#pragma unroll
    for (int j = 0; j < 8; j++) onesu.s[j] = 0x3F80;
    bf16x8 ones = onesu.v;

    int q16 = lane & 15, krow = lane >> 4;
    const u16* vtb = VT + (size_t)(b * 128 + h * 16 + q16) * 2048;
    u16* pw = pbuf + wave * 1280 + m * 40 + kg * 4;
    const u16* pr0 = pbuf + wave * 1280 + q16 * 40 + krow * 8;
    const u16* pr1 = pr0 + 16 * 40;

    for (int t = t0; t < t0 + 512; t += 32) {
        bf16x8 kh8 = ld_bf8(kbh + (size_t)(t + m) * 16 + kg * 8);
        bf16x8 kl8 = ld_bf8(kbl + (size_t)(t + m) * 16 + kg * 8);
        f32x16 ci = *(const f32x16*)(biasC + (t >> 5) * 32 + kg * 16);
        f32x16 sc = __builtin_amdgcn_mfma_f32_32x32x16_bf16(kh8, qfl, ci, 0, 0, 0);
        sc = __builtin_amdgcn_mfma_f32_32x32x16_bf16(kl8, qfh, sc, 0, 0, 0);
        sc = __builtin_amdgcn_mfma_f32_32x32x16_bf16(kh8, qfh, sc, 0, 0, 0);
#pragma unroll
        for (int rg = 0; rg < 4; rg++) {
            float e0 = __builtin_amdgcn_exp2f(sc[rg * 4 + 0] - mrow);
            float e1 = __builtin_amdgcn_exp2f(sc[rg * 4 + 1] - mrow);
            float e2 = __builtin_amdgcn_exp2f(sc[rg * 4 + 2] - mrow);
            float e3 = __builtin_amdgcn_exp2f(sc[rg * 4 + 3] - mrow);
            u32x2 pk;
            pk[0] = __builtin_amdgcn_perm(__builtin_bit_cast(u32, e1),
                                          __builtin_bit_cast(u32, e0), 0x07060302u);
            pk[1] = __builtin_amdgcn_perm(__builtin_bit_cast(u32, e3),
                                          __builtin_bit_cast(u32, e2), 0x07060302u);
            *(u32x2*)(pw + rg * 8) = pk;     // keys rg*8+4kg..+3 for query m
        }
        bf16x8 vf = ld_bf8(vtb + t + krow * 8);
        bf16x8 p0 = *(const bf16x8*)pr0;
        bf16x8 p1 = *(const bf16x8*)pr1;
        o0 = __builtin_amdgcn_mfma_f32_16x16x32_bf16(p0, vf, o0, 0, 0, 0);
        o1 = __builtin_amdgcn_mfma_f32_16x16x32_bf16(p1, vf, o1, 0, 0, 0);
        l0 = __builtin_amdgcn_mfma_f32_16x16x32_bf16(p0, ones, l0, 0, 0, 0);
        l1 = __builtin_amdgcn_mfma_f32_16x16x32_bf16(p1, ones, l1, 0, 0, 0);
    }

    __syncthreads();     // all P-tile reads done before obuf/lbuf alias writes

    *(f32x4*)(obuf + wave * 512 + q16 * 32 + krow * 4)      = o0;
    *(f32x4*)(obuf + wave * 512 + q16 * 32 + krow * 4 + 16) = o1;
    if (q16 == 0) {
        *(f32x4*)(lbuf + wave * 32 + krow * 4)      = l0;
        *(f32x4*)(lbuf + wave * 32 + krow * 4 + 16) = l1;
    }
    __syncthreads();

    int dd = threadIdx.x & 15, q = threadIdx.x >> 4;
    int slot0 = (h == 0) ? 0 : h + 1;
#pragma unroll
    for (int hf = 0; hf < 2; hf++) {
        int qq = q + hf * 16;
        float os = obuf[0 * 512 + dd * 32 + qq] + obuf[1 * 512 + dd * 32 + qq]
                 + obuf[2 * 512 + dd * 32 + qq] + obuf[3 * 512 + dd * 32 + qq];
        float ls = lbuf[0 * 32 + qq] + lbuf[1 * 32 + qq]
                 + lbuf[2 * 32 + qq] + lbuf[3 * 32 + qq];
        u16 vb = f2b_rne(os * __builtin_amdgcn_rcpf(ls));
        int orow = b * 2048 + qs + qq;
        AO[orow * 128 + slot0 * 16 + dd] = vb;
        if (h == 1) AO[orow * 128 + 16 + dd] = vb;
    }
}

// ---------------------------------------------------------------------------
// final linear: out = AO(bf16) @ lin_w^T + lin_b (lin_w converted in-reg).
// ---------------------------------------------------------------------------
__global__ __launch_bounds__(256) void fin_kernel(
    const u16* __restrict__ AO, const float* __restrict__ lw,
    const float* __restrict__ lb, float* out)
{
    int ct   = threadIdx.x >> 6;
    int lane = threadIdx.x & 63;
    int m = lane & 31, kg = lane >> 5;
    int r0 = blockIdx.x * 32;
    int c = ct * 32 + m;

    f32x16 acc = zero16();
    for (int kk = 0; kk < 128; kk += 16) {
        bf16x8 af = ld_bf8(AO + (size_t)(r0 + m) * 128 + kk + kg * 8);
        const float* wp = lw + (size_t)c * 128 + kk + kg * 8;
        f32x4 w0 = *(const f32x4*)wp;
        f32x4 w1 = *(const f32x4*)(wp + 4);
        BF8 bfr;
#pragma unroll
        for (int j = 0; j < 4; j++) {
            bfr.s[j]     = f2b_rne(w0[j]);
            bfr.s[4 + j] = f2b_rne(w1[j]);
        }
        acc = __builtin_amdgcn_mfma_f32_32x32x16_bf16(af, bfr.v, acc, 0, 0, 0);
    }
    float bias = lb[c];
#pragma unroll
    for (int r = 0; r < 16; r++) {
        int row = (r & 3) + 8 * (r >> 2) + 4 * kg;
        out[(size_t)(r0 + row) * 128 + c] = acc[r] + bias;
    }
}

// ---------------------------------------------------------------------------
extern "C" void kernel_launch(void* const* d_in, const int* in_sizes, int n_in,
                              void* d_out, int out_size, void* d_ws, size_t ws_size,
                              hipStream_t stream)
{
    const float* x    = (const float*)d_in[0];
    const int*   mask = (const int*)d_in[1];
    const float* wq   = (const float*)d_in[2];
    const float* wk   = (const float*)d_in[3];
    const float* wv   = (const float*)d_in[4];
    const float* lw   = (const float*)d_in[5];
    const float* lb   = (const float*)d_in[6];
    float* out = (float*)d_out;

    char* ws = (char*)d_ws;
    u16* Qph = (u16*)(ws + 0 * 2097152);
    u16* Qpl = (u16*)(ws + 1 * 2097152);
    u16* Kph = (u16*)(ws + 2 * 2097152);
    u16* Kpl = (u16*)(ws + 3 * 2097152);
    u16* VT  = (u16*)(ws + 4 * 2097152);
    u16* AO  = (u16*)(ws + 5 * 2097152);

    proj_kernel<<<dim3(256, 3), 256, 0, stream>>>(x, wq, wk, wv,
                                                  Qph, Qpl, Kph, Kpl, VT);
    attn_kernel<<<1792, 256, 0, stream>>>(Qph, Qpl, Kph, Kpl, VT, mask, AO);
    fin_kernel<<<256, 256, 0, stream>>>(AO, lw, lb, out);
}